// Round 2
// baseline (818.914 us; speedup 1.0000x reference)
//
#include <hip/hip_runtime.h>
#include <hip/hip_cooperative_groups.h>
#include <math.h>

namespace cg = cooperative_groups;

#define N_NODES 21
#define NODE_FEAT 128
#define N_ACTIONS 256

// ws float layout:
//   [0, 448)     v (441 used)
//   [448, 960)   acc1 (512)
//   [960, 1472)  acc2 (512)
//   [1472, 1728) acc3 (256)
#define WS_V    0
#define WS_ACC1 448
#define WS_ACC2 960
#define WS_ACC3 1472

// Single cooperative kernel: 64 blocks x 256 threads.
// Stage 0: block 0 = GCN (entirely in LDS), block 1 = zero accumulators.
// Stage 1: fc1 split-K (blocks 0..62, 7 rows each), atomics into acc1.
// Stage 2: fc2 split-K (all 64 blocks, 8 rows each), fuses relu(acc1+bf1).
// Stage 3: fc3 split-K (blocks 0..31, 16 rows each), fuses relu(acc2+bf2).
// Stage 4: block 0 writes out = relu(acc3 + bf3).
__global__ __launch_bounds__(256) void fused_kernel(
    const float* __restrict__ state,      // [B,21,128], only batch 0 used
    const int*   __restrict__ edge_index, // [2,128]
    const float* __restrict__ W1,         // [128,21]
    const float* __restrict__ b1,         // [21]
    const float* __restrict__ W2,         // [21,21]
    const float* __restrict__ b2,         // [21]
    const float* __restrict__ Wf1,        // [441,512]
    const float* __restrict__ bf1,        // [512]
    const float* __restrict__ Wf2,        // [512,512]
    const float* __restrict__ bf2,        // [512]
    const float* __restrict__ Wf3,        // [512,256]
    const float* __restrict__ bf3,        // [256]
    float* __restrict__ ws,
    float* __restrict__ out)
{
    cg::grid_group grid = cg::this_grid();
    const int b = blockIdx.x;
    const int t = threadIdx.x;

    float* v    = ws + WS_V;
    float* acc1 = ws + WS_ACC1;
    float* acc2 = ws + WS_ACC2;
    float* acc3 = ws + WS_ACC3;

    // ---------------- Stage 0 ----------------
    if (b == 0) {
        __shared__ float sA[441];
        __shared__ float sX[N_NODES * NODE_FEAT];   // 2688
        __shared__ float sW1[NODE_FEAT * 21];       // 2688
        __shared__ float sW2[441];
        __shared__ float sh[441];
        __shared__ float sg[441];
        __shared__ float sdinv[N_NODES];

        for (int i = t; i < 441; i += 256) sA[i] = 0.0f;
        __syncthreads();

        // scatter-add edges: A[row,col] += 1
        if (t < 128) {
            int r = edge_index[t];
            int c = edge_index[128 + t];
            atomicAdd(&sA[r * 21 + c], 1.0f);
        }
        __syncthreads();

        // self loops
        if (t < 21) sA[t * 22] += 1.0f;
        __syncthreads();

        // deg = column sums; dinv = 1/sqrt(deg)
        if (t < 21) {
            float d = 0.0f;
            for (int i = 0; i < 21; ++i) d += sA[i * 21 + t];
            sdinv[t] = 1.0f / sqrtf(d);
        }
        __syncthreads();

        // A_norm[i,j] = dinv[i]*A[i,j]*dinv[j]; stage X, W1, W2
        for (int i = t; i < 441; i += 256) {
            int r = i / 21, c = i % 21;
            sA[i] = sdinv[r] * sA[i] * sdinv[c];
        }
        for (int i = t; i < N_NODES * NODE_FEAT; i += 256) {
            sX[i]  = state[i];
            sW1[i] = W1[i];
        }
        for (int i = t; i < 441; i += 256) sW2[i] = W2[i];
        __syncthreads();

        // h1[n,k] = sum_f X[n,f] * W1[f,k]
        for (int i = t; i < 441; i += 256) {
            int n = i / 21, k = i % 21;
            float s = 0.0f;
            for (int f = 0; f < NODE_FEAT; ++f) s += sX[n * NODE_FEAT + f] * sW1[f * 21 + k];
            sh[i] = s;
        }
        __syncthreads();

        // g1[i,k] = b1[k] + sum_j A[i,j] * h1[j,k]
        for (int i = t; i < 441; i += 256) {
            int n = i / 21, k = i % 21;
            float s = b1[k];
            for (int j = 0; j < 21; ++j) s += sA[n * 21 + j] * sh[j * 21 + k];
            sg[i] = s;
        }
        __syncthreads();

        // h2[n,k] = sum_f g1[n,f] * W2[f,k]
        for (int i = t; i < 441; i += 256) {
            int n = i / 21, k = i % 21;
            float s = 0.0f;
            for (int f = 0; f < 21; ++f) s += sg[n * 21 + f] * sW2[f * 21 + k];
            sh[i] = s;
        }
        __syncthreads();

        // v[n*21+k] = b2[k] + sum_j A[n,j] * h2[j,k]
        for (int i = t; i < 441; i += 256) {
            int n = i / 21, k = i % 21;
            float s = b2[k];
            for (int j = 0; j < 21; ++j) s += sA[n * 21 + j] * sh[j * 21 + k];
            v[i] = s;
        }
    } else if (b == 1) {
        for (int i = t; i < 512; i += 256) {
            acc1[i] = 0.0f;
            acc2[i] = 0.0f;
        }
        acc3[t] = 0.0f;
    }
    grid.sync();

    // ---------------- Stage 1: fc1 (441 -> 512), blocks 0..62, 7 rows each ----------------
    if (b < 63) {
        const int r0 = b * 7;
        float s0 = 0.0f, s1 = 0.0f;
        #pragma unroll
        for (int r = 0; r < 7; ++r) {
            float vl = v[r0 + r];
            const float* row = Wf1 + (size_t)(r0 + r) * 512;
            s0 += vl * row[t];
            s1 += vl * row[t + 256];
        }
        atomicAdd(&acc1[t], s0);
        atomicAdd(&acc1[t + 256], s1);
    }
    grid.sync();

    // ---------------- Stage 2: fc2 (512 -> 512), all 64 blocks, 8 rows each ----------------
    {
        const int r0 = b * 8;
        float s0 = 0.0f, s1 = 0.0f;
        #pragma unroll
        for (int r = 0; r < 8; ++r) {
            float a = acc1[r0 + r] + bf1[r0 + r];
            a = a > 0.0f ? a : 0.0f;
            const float* row = Wf2 + (size_t)(r0 + r) * 512;
            s0 += a * row[t];
            s1 += a * row[t + 256];
        }
        atomicAdd(&acc2[t], s0);
        atomicAdd(&acc2[t + 256], s1);
    }
    grid.sync();

    // ---------------- Stage 3: fc3 (512 -> 256), blocks 0..31, 16 rows each ----------------
    if (b < 32) {
        const int r0 = b * 16;
        float s = 0.0f;
        #pragma unroll
        for (int r = 0; r < 16; ++r) {
            float a = acc2[r0 + r] + bf2[r0 + r];
            a = a > 0.0f ? a : 0.0f;
            s += a * Wf3[(size_t)(r0 + r) * 256 + t];
        }
        atomicAdd(&acc3[t], s);
    }
    grid.sync();

    // ---------------- Stage 4: finalize ----------------
    if (b == 0) {
        float a = acc3[t] + bf3[t];
        out[t] = a > 0.0f ? a : 0.0f;
    }
}

extern "C" void kernel_launch(void* const* d_in, const int* in_sizes, int n_in,
                              void* d_out, int out_size, void* d_ws, size_t ws_size,
                              hipStream_t stream)
{
    const float* state      = (const float*)d_in[0];
    const int*   edge_index = (const int*)  d_in[1];
    const float* W1  = (const float*)d_in[2];
    const float* b1  = (const float*)d_in[3];
    const float* W2  = (const float*)d_in[4];
    const float* b2  = (const float*)d_in[5];
    const float* Wf1 = (const float*)d_in[6];
    const float* bf1 = (const float*)d_in[7];
    const float* Wf2 = (const float*)d_in[8];
    const float* bf2 = (const float*)d_in[9];
    const float* Wf3 = (const float*)d_in[10];
    const float* bf3 = (const float*)d_in[11];

    float* ws  = (float*)d_ws;
    float* out = (float*)d_out;

    void* args[] = {
        (void*)&state, (void*)&edge_index,
        (void*)&W1, (void*)&b1, (void*)&W2, (void*)&b2,
        (void*)&Wf1, (void*)&bf1, (void*)&Wf2, (void*)&bf2,
        (void*)&Wf3, (void*)&bf3,
        (void*)&ws, (void*)&out
    };
    hipLaunchCooperativeKernel((void*)fused_kernel, dim3(64), dim3(256),
                               args, 0, stream);
}